// Round 4
// baseline (1052.242 us; speedup 1.0000x reference)
//
#include <hip/hip_runtime.h>
#include <hip/hip_fp16.h>
#include <stdint.h>

#define M_TOK 8192
#define KD 4096
#define ND 4096

using i32x4 = __attribute__((ext_vector_type(4))) int;

typedef const __attribute__((address_space(1))) void* gp_t;
typedef __attribute__((address_space(3))) void* lp_t;

// ---------------- Kernel 1: fused per-token quant (blocks 0..8191) + weight pack (blocks 8192..) ----------------
__global__ __launch_bounds__(256) void prep_kernel(
    const float* __restrict__ x,
    int8_t* __restrict__ q,
    float* __restrict__ scales,
    const int* __restrict__ w32,
    int8_t* __restrict__ w8)
{
    const int t = threadIdx.x;
    if (blockIdx.x >= 8192) {
        // ---- pack int32 weights -> int8 ----
        const int b = blockIdx.x - 8192;          // 0..4095
        const int4* w4 = (const int4*)w32;
        int* q32 = (int*)w8;
        #pragma unroll
        for (int u = 0; u < 4; ++u) {
            int g = b * 1024 + u * 256 + t;
            int4 a = w4[g];
            q32[g] = (a.x & 255) | ((a.y & 255) << 8) | ((a.z & 255) << 16) | (a.w << 24);
        }
        return;
    }

    // ---- per-token absmax fake-quant (f32-widened f16 input) ----
    const int row  = blockIdx.x;
    const int lane = t & 63;
    const int wave = t >> 6;

    const float4* xr = (const float4*)(x + (size_t)row * KD);
    float4 p[4];
    #pragma unroll
    for (int i = 0; i < 4; ++i) p[i] = xr[i * 256 + t];

    float am = 0.0f;
    #pragma unroll
    for (int i = 0; i < 4; ++i) {
        am = fmaxf(am, fmaxf(fmaxf(fabsf(p[i].x), fabsf(p[i].y)),
                             fmaxf(fabsf(p[i].z), fabsf(p[i].w))));
    }
    #pragma unroll
    for (int off = 32; off >= 1; off >>= 1)
        am = fmaxf(am, __shfl_xor(am, off));

    __shared__ float smax[4];
    if (lane == 0) smax[wave] = am;
    __syncthreads();
    am = fmaxf(fmaxf(smax[0], smax[1]), fmaxf(smax[2], smax[3]));

    float s = __half2float(__float2half(am * (1.0f / 127.0f)));
    s = fmaxf(s, 1e-30f);
    const float inv = 1.0f / s;

    int* qr = (int*)(q + (size_t)row * KD);
    #pragma unroll
    for (int i = 0; i < 4; ++i) {
        float vv[4] = {p[i].x, p[i].y, p[i].z, p[i].w};
        int w32v = 0;
        #pragma unroll
        for (int e = 0; e < 4; ++e) {
            float tq = __half2float(__float2half(vv[e] * inv));
            int qi = (int)rintf(tq);
            qi = max(-127, min(127, qi));
            w32v |= (qi & 255) << (8 * e);
        }
        qr[i * 256 + t] = w32v;
    }
    if (t == 0) scales[row] = s;
}

// ---------------- 8-phase-per-2kt -> 4-phase-per-kt 256x256 int8 GEMM, single-buffer 4-region rotation ----------------
// LDS per operand: [256 rows][128 B], XOR-swizzled: phys_col = col ^ ((row&7)<<4).
// Regions: A-half0 / A-half1 / B-half0 / B-half1 (16 KiB each, 64 KiB total) -> 2 blocks/CU.

__device__ __forceinline__ void stage_half(
    const int8_t* __restrict__ gbase,   // panel base (tile row 0)
    int half, int kbyte,
    char* ldst,                         // lds operand base
    int tid)
{
    const int w    = tid >> 6;
    const int lane = tid & 63;
    #pragma unroll
    for (int qq = 0; qq < 2; ++qq) {
        const int d  = qq * 8192 + w * 1024 + lane * 16;
        const int r  = d >> 7;                  // 0..127 within half
        const int c  = d & 127;
        const int cs = c ^ ((r & 7) << 4);      // inverse swizzle on source (rule #21)
        const int8_t* src = gbase + (size_t)(half * 128 + r) * KD + kbyte + cs;
        __builtin_amdgcn_global_load_lds((gp_t)src,
            (lp_t)(ldst + half * 16384 + qq * 8192 + w * 1024), 16, 0, 0);
    }
}

template<int MH>
__device__ __forceinline__ void read_A(const char* lA, int wr, int lane, i32x4 (&a)[4][2]) {
    const int l15 = lane & 15;
    const int cg  = (lane >> 4) << 4;
    #pragma unroll
    for (int mf = 0; mf < 4; ++mf) {
        const int row = MH * 128 + wr * 64 + mf * 16 + l15;
        const int sw  = (row & 7) << 4;
        #pragma unroll
        for (int ks = 0; ks < 2; ++ks)
            a[mf][ks] = *(const i32x4*)(lA + row * 128 + ((ks * 64 + cg) ^ sw));
    }
}

template<int NH>
__device__ __forceinline__ void read_B(const char* lB, int wc, int lane, i32x4 (&b)[2][2]) {
    const int l15 = lane & 15;
    const int cg  = (lane >> 4) << 4;
    #pragma unroll
    for (int nf = 0; nf < 2; ++nf) {
        const int row = NH * 128 + wc * 32 + nf * 16 + l15;
        const int sw  = (row & 7) << 4;
        #pragma unroll
        for (int ks = 0; ks < 2; ++ks)
            b[nf][ks] = *(const i32x4*)(lB + row * 128 + ((ks * 64 + cg) ^ sw));
    }
}

template<int MH, int NH>
__device__ __forceinline__ void mfma_quad(i32x4 (&acc)[2][4][2][2],
                                          const i32x4 (&a)[4][2],
                                          const i32x4 (&b)[2][2]) {
    __builtin_amdgcn_s_setprio(1);
    #pragma unroll
    for (int mf = 0; mf < 4; ++mf)
        #pragma unroll
        for (int nf = 0; nf < 2; ++nf)
            #pragma unroll
            for (int ks = 0; ks < 2; ++ks)
                acc[MH][mf][NH][nf] =
                    __builtin_amdgcn_mfma_i32_16x16x64_i8(a[mf][ks], b[nf][ks],
                                                          acc[MH][mf][NH][nf], 0, 0, 0);
    __builtin_amdgcn_s_setprio(0);
}

#define BAR() do { __builtin_amdgcn_s_barrier(); __builtin_amdgcn_sched_barrier(0); } while (0)

__global__ __launch_bounds__(512, 4) void gemm_q8_8ph_kernel(
    const int8_t* __restrict__ q,
    const int8_t* __restrict__ w8,
    const float* __restrict__ qs,
    const float* __restrict__ wscale,
    const float* __restrict__ bias,
    float* __restrict__ y)
{
    __shared__ char lds[2][32768];   // [A/B][256 rows x 128 B] single buffer, 64 KiB

    const int tid  = threadIdx.x;
    const int lane = tid & 63;
    const int wave = tid >> 6;
    const int wr   = wave >> 2;   // 0..1
    const int wc   = wave & 3;    // 0..3
    const int tn   = blockIdx.x;  // 0..15
    const int tm   = blockIdx.y;  // 0..31

    const int8_t* gA = q  + (size_t)(tm * 256) * KD;
    const int8_t* gB = w8 + (size_t)(tn * 256) * KD;

    char* lA = &lds[0][0];
    char* lB = &lds[1][0];

    i32x4 acc[2][4][2][2] = {};
    i32x4 a[4][2], b0[2][2], b1[2][2];

    // prologue (order matters for steady-state fence counts): A0, B0, B1, A1 of kt=0
    stage_half(gA, 0, 0, lA, tid);
    stage_half(gB, 0, 0, lB, tid);
    stage_half(gB, 1, 0, lB, tid);
    stage_half(gA, 1, 0, lA, tid);
    asm volatile("s_waitcnt vmcnt(4)");   // A0,B0 landed (B1,A1 may be in flight)
    BAR();

    for (int kt = 0; kt < 32; ++kt) {
        const int kb = ((kt + 1) & 31) * 128;   // kt=31 wraps: harmless garbage refresh

        // phase 1: read A0,B0 (kt); mfma(0,0); fence -> B1(kt) landed
        read_A<0>(lA, wr, lane, a);
        read_B<0>(lB, wc, lane, b0);
        BAR();
        mfma_quad<0, 0>(acc, a, b0);
        asm volatile("s_waitcnt vmcnt(2)");
        BAR();

        // phase 2: read B1 (kt); stage A0,B0(kt+1); mfma(0,1); fence -> A1(kt) landed
        read_B<1>(lB, wc, lane, b1);
        stage_half(gA, 0, kb, lA, tid);
        stage_half(gB, 0, kb, lB, tid);
        BAR();
        mfma_quad<0, 1>(acc, a, b1);
        asm volatile("s_waitcnt vmcnt(4)");
        BAR();

        // phase 3: read A1 (kt); stage B1(kt+1); mfma(1,0)
        read_A<1>(lA, wr, lane, a);
        stage_half(gB, 1, kb, lB, tid);
        BAR();
        mfma_quad<1, 0>(acc, a, b0);
        BAR();

        // phase 4: stage A1(kt+1); mfma(1,1); fence -> A0,B0(kt+1) landed
        stage_half(gA, 1, kb, lA, tid);
        BAR();
        mfma_quad<1, 1>(acc, a, b1);
        asm volatile("s_waitcnt vmcnt(4)");
        BAR();
    }
    asm volatile("s_waitcnt vmcnt(0)");   // drain wrap-stages before endpgm

    // epilogue: C/D layout col = lane&15, row = (lane>>4)*4 + reg
    #pragma unroll
    for (int mh = 0; mh < 2; ++mh)
        #pragma unroll
        for (int mf = 0; mf < 4; ++mf) {
            const int rm = tm * 256 + mh * 128 + wr * 64 + mf * 16 + ((lane >> 4) << 2);
            float qsv[4];
            #pragma unroll
            for (int r = 0; r < 4; ++r) qsv[r] = qs[rm + r];
            #pragma unroll
            for (int nh = 0; nh < 2; ++nh)
                #pragma unroll
                for (int nf = 0; nf < 2; ++nf) {
                    const int n = tn * 256 + nh * 128 + wc * 32 + nf * 16 + (lane & 15);
                    const float wn = wscale[n];
                    const float bn = bias[n];
                    #pragma unroll
                    for (int r = 0; r < 4; ++r)
                        y[(size_t)(rm + r) * ND + n] =
                            (float)acc[mh][mf][nh][nf][r] * (qsv[r] * wn) + bn;
                }
        }
}

// ---------------- Fallback GEMM (no-workspace path): 128^2 m97 structure, reads w32 ----------------
__global__ __launch_bounds__(256, 2) void gemm_q8_fallback(
    const int8_t* __restrict__ q,
    const int* __restrict__ w32,
    const float* __restrict__ qs,
    const float* __restrict__ wscale,
    const float* __restrict__ bias,
    float* __restrict__ y)
{
    __shared__ int8_t lA[128 * 64];
    __shared__ int8_t lB[128 * 64];

    const int tid  = threadIdx.x;
    const int lane = tid & 63;
    const int wave = tid >> 6;
    const int wr   = wave >> 1;
    const int wc   = wave & 1;
    const int tn   = blockIdx.x;
    const int tm   = blockIdx.y;

    const int ci0  = wave * 2;
    const int off0 = ci0 * 1024 + lane * 16;
    const int r0   = off0 >> 6;
    const int c0   = off0 & 63;
    const int off1 = off0 + 1024;
    const int r1   = off1 >> 6;
    const int c1   = off1 & 63;

    const int8_t* gA0 = q + (size_t)(tm * 128 + r0) * KD + c0;
    const int8_t* gA1 = q + (size_t)(tm * 128 + r1) * KD + c1;

    const int brow  = tid >> 1;
    const int bhalf = tid & 1;
    const int* gW = w32 + (size_t)(tn * 128 + brow) * KD + bhalf * 32;

    i32x4 acc[4][4] = {};
    const int kc = (lane >> 4) * 16;
    const int rA = wr * 64 + (lane & 15);
    const int rB = wc * 64 + (lane & 15);

    for (int k0 = 0; k0 < KD; k0 += 64) {
        __builtin_amdgcn_global_load_lds((gp_t)(gA0 + k0), (lp_t)(lA + ci0 * 1024),        16, 0, 0);
        __builtin_amdgcn_global_load_lds((gp_t)(gA1 + k0), (lp_t)(lA + ci0 * 1024 + 1024), 16, 0, 0);
        int bw[8];
        #pragma unroll
        for (int u = 0; u < 8; ++u) {
            i32x4 a4 = *(const i32x4*)(gW + k0 + u * 4);
            bw[u] = (a4[0] & 255) | ((a4[1] & 255) << 8) | ((a4[2] & 255) << 16) | (a4[3] << 24);
        }
        *(i32x4*)(lB + brow * 64 + bhalf * 32)      = i32x4{bw[0], bw[1], bw[2], bw[3]};
        *(i32x4*)(lB + brow * 64 + bhalf * 32 + 16) = i32x4{bw[4], bw[5], bw[6], bw[7]};
        __syncthreads();

        i32x4 a[4], b[4];
        #pragma unroll
        for (int i = 0; i < 4; ++i) a[i] = *(const i32x4*)(lA + (rA + i * 16) * 64 + kc);
        #pragma unroll
        for (int j = 0; j < 4; ++j) b[j] = *(const i32x4*)(lB + (rB + j * 16) * 64 + kc);
        #pragma unroll
        for (int i = 0; i < 4; ++i)
            #pragma unroll
            for (int j = 0; j < 4; ++j)
                acc[i][j] = __builtin_amdgcn_mfma_i32_16x16x64_i8(a[i], b[j], acc[i][j], 0, 0, 0);
        __syncthreads();
    }

    const int cbase = tn * 128 + wc * 64 + (lane & 15);
    const int rbase = tm * 128 + wr * 64 + ((lane >> 4) << 2);
    #pragma unroll
    for (int j = 0; j < 4; ++j) {
        const int n  = cbase + j * 16;
        const float wn = wscale[n];
        const float bn = bias[n];
        #pragma unroll
        for (int i = 0; i < 4; ++i)
            #pragma unroll
            for (int r = 0; r < 4; ++r) {
                const int m = rbase + i * 16 + r;
                y[(size_t)m * ND + n] = (float)acc[i][j][r] * (qs[m] * wn) + bn;
            }
    }
}

extern "C" void kernel_launch(void* const* d_in, const int* in_sizes, int n_in,
                              void* d_out, int out_size, void* d_ws, size_t ws_size,
                              hipStream_t stream) {
    const float* x      = (const float*)d_in[0];
    const int*   w32    = (const int*)d_in[1];
    const float* wscale = (const float*)d_in[2];
    const float* bias   = (const float*)d_in[3];
    float*       y      = (float*)d_out;

    const size_t q_bytes  = (size_t)M_TOK * KD;
    const size_t s_bytes  = (size_t)M_TOK * sizeof(float);
    const size_t w8_bytes = (size_t)ND * KD;

    int8_t* qbuf   = (int8_t*)d_ws;
    float*  scales = (float*)((char*)d_ws + q_bytes);
    int8_t* w8     = (int8_t*)((char*)d_ws + q_bytes + s_bytes);

    if (ws_size >= q_bytes + s_bytes + w8_bytes) {
        prep_kernel<<<8192 + 4096, 256, 0, stream>>>(x, qbuf, scales, w32, w8);
        dim3 grid(ND / 256, M_TOK / 256);
        gemm_q8_8ph_kernel<<<grid, 512, 0, stream>>>(qbuf, w8, scales, wscale, bias, y);
    } else {
        prep_kernel<<<8192, 256, 0, stream>>>(x, qbuf, scales, w32, w8);
        dim3 grid(ND / 128, M_TOK / 128);
        gemm_q8_fallback<<<grid, 256, 0, stream>>>(qbuf, w32, scales, wscale, bias, y);
    }
}

// Round 5
// 173.419 us; speedup vs baseline: 6.0676x; 6.0676x over previous
//
#include <hip/hip_runtime.h>
#include <hip/hip_fp16.h>
#include <stdint.h>

#define M_TOK 8192
#define KD 4096
#define ND 4096

using i32x4 = __attribute__((ext_vector_type(4))) int;

typedef const __attribute__((address_space(1))) void* gp_t;
typedef __attribute__((address_space(3))) void* lp_t;

// ---------------- Kernel 1: fused per-token quant (blocks 0..8191) + weight pack (blocks 8192..) ----------------
__global__ __launch_bounds__(256) void prep_kernel(
    const float* __restrict__ x,
    int8_t* __restrict__ q,
    float* __restrict__ scales,
    const int* __restrict__ w32,
    int8_t* __restrict__ w8)
{
    const int t = threadIdx.x;
    if (blockIdx.x >= 8192) {
        const int b = blockIdx.x - 8192;          // 0..4095
        const int4* w4 = (const int4*)w32;
        int* q32 = (int*)w8;
        #pragma unroll
        for (int u = 0; u < 4; ++u) {
            int g = b * 1024 + u * 256 + t;
            int4 a = w4[g];
            q32[g] = (a.x & 255) | ((a.y & 255) << 8) | ((a.z & 255) << 16) | (a.w << 24);
        }
        return;
    }

    const int row  = blockIdx.x;
    const int lane = t & 63;
    const int wave = t >> 6;

    const float4* xr = (const float4*)(x + (size_t)row * KD);
    float4 p[4];
    #pragma unroll
    for (int i = 0; i < 4; ++i) p[i] = xr[i * 256 + t];

    float am = 0.0f;
    #pragma unroll
    for (int i = 0; i < 4; ++i) {
        am = fmaxf(am, fmaxf(fmaxf(fabsf(p[i].x), fabsf(p[i].y)),
                             fmaxf(fabsf(p[i].z), fabsf(p[i].w))));
    }
    #pragma unroll
    for (int off = 32; off >= 1; off >>= 1)
        am = fmaxf(am, __shfl_xor(am, off));

    __shared__ float smax[4];
    if (lane == 0) smax[wave] = am;
    __syncthreads();
    am = fmaxf(fmaxf(smax[0], smax[1]), fmaxf(smax[2], smax[3]));

    float s = __half2float(__float2half(am * (1.0f / 127.0f)));
    s = fmaxf(s, 1e-30f);
    const float inv = 1.0f / s;

    int* qr = (int*)(q + (size_t)row * KD);
    #pragma unroll
    for (int i = 0; i < 4; ++i) {
        float vv[4] = {p[i].x, p[i].y, p[i].z, p[i].w};
        int w32v = 0;
        #pragma unroll
        for (int e = 0; e < 4; ++e) {
            float tq = __half2float(__float2half(vv[e] * inv));
            int qi = (int)rintf(tq);
            qi = max(-127, min(127, qi));
            w32v |= (qi & 255) << (8 * e);
        }
        qr[i * 256 + t] = w32v;
    }
    if (t == 0) scales[row] = s;
}

// ---------------- 8-phase 256x256 int8 GEMM (round-3 proven schedule) + nt-store + XCD swizzle ----------------
// LDS per buffer per operand: [256 rows][128 B], XOR-swizzled: phys_col = col ^ ((row&7)<<4).
// Staged via global_load_lds (linear dest) with inverse-swizzled per-lane GLOBAL source (rule #21).

__device__ __forceinline__ void stage_half(
    const int8_t* __restrict__ gbase,   // panel base (tile row 0)
    int half, int kbyte,
    char* ldst,                         // lds operand base (buffer selected)
    int tid)
{
    const int w    = tid >> 6;
    const int lane = tid & 63;
    #pragma unroll
    for (int qq = 0; qq < 2; ++qq) {
        const int d  = qq * 8192 + w * 1024 + lane * 16;
        const int r  = d >> 7;                  // 0..127 within half
        const int c  = d & 127;
        const int cs = c ^ ((r & 7) << 4);      // inverse swizzle on source
        const int8_t* src = gbase + (size_t)(half * 128 + r) * KD + kbyte + cs;
        __builtin_amdgcn_global_load_lds((gp_t)src,
            (lp_t)(ldst + half * 16384 + qq * 8192 + w * 1024), 16, 0, 0);
    }
}

template<int MH>
__device__ __forceinline__ void read_A(const char* lA, int wr, int lane, i32x4 (&a)[4][2]) {
    const int l15 = lane & 15;
    const int cg  = (lane >> 4) << 4;
    #pragma unroll
    for (int mf = 0; mf < 4; ++mf) {
        const int row = MH * 128 + wr * 64 + mf * 16 + l15;
        const int sw  = (row & 7) << 4;
        #pragma unroll
        for (int ks = 0; ks < 2; ++ks)
            a[mf][ks] = *(const i32x4*)(lA + row * 128 + ((ks * 64 + cg) ^ sw));
    }
}

template<int NH>
__device__ __forceinline__ void read_B(const char* lB, int wc, int lane, i32x4 (&b)[2][2]) {
    const int l15 = lane & 15;
    const int cg  = (lane >> 4) << 4;
    #pragma unroll
    for (int nf = 0; nf < 2; ++nf) {
        const int row = NH * 128 + wc * 32 + nf * 16 + l15;
        const int sw  = (row & 7) << 4;
        #pragma unroll
        for (int ks = 0; ks < 2; ++ks)
            b[nf][ks] = *(const i32x4*)(lB + row * 128 + ((ks * 64 + cg) ^ sw));
    }
}

template<int MH, int NH>
__device__ __forceinline__ void mfma_quad(i32x4 (&acc)[2][4][2][2],
                                          const i32x4 (&a)[4][2],
                                          const i32x4 (&b)[2][2]) {
    __builtin_amdgcn_s_setprio(1);
    #pragma unroll
    for (int mf = 0; mf < 4; ++mf)
        #pragma unroll
        for (int nf = 0; nf < 2; ++nf)
            #pragma unroll
            for (int ks = 0; ks < 2; ++ks)
                acc[MH][mf][NH][nf] =
                    __builtin_amdgcn_mfma_i32_16x16x64_i8(a[mf][ks], b[nf][ks],
                                                          acc[MH][mf][NH][nf], 0, 0, 0);
    __builtin_amdgcn_s_setprio(0);
}

#define BAR() do { __builtin_amdgcn_s_barrier(); __builtin_amdgcn_sched_barrier(0); } while (0)

__global__ __launch_bounds__(512, 2) void gemm_q8_8ph_kernel(
    const int8_t* __restrict__ q,
    const int8_t* __restrict__ w8,
    const float* __restrict__ qs,
    const float* __restrict__ wscale,
    const float* __restrict__ bias,
    float* __restrict__ y)
{
    __shared__ char lds[2][2][32768];   // [buf][A/B][256 rows x 128 B]

    const int tid  = threadIdx.x;
    const int lane = tid & 63;
    const int wave = tid >> 6;
    const int wr   = wave >> 2;   // 0..1
    const int wc   = wave & 3;    // 0..3

    // XCD-chunked bijective swizzle: 512 blocks, 8 XCDs, 64 blocks/XCD chunk.
    // Within a chunk, consecutive sids share tm (A panel x16) and revisit tn (B panel x4).
    const int bid = blockIdx.x;               // 0..511
    const int sid = (bid & 7) * 64 + (bid >> 3);
    const int tn  = sid & 15;                 // 0..15
    const int tm  = sid >> 4;                 // 0..31

    const int8_t* gA = q  + (size_t)(tm * 256) * KD;
    const int8_t* gB = w8 + (size_t)(tn * 256) * KD;

    char* lA0 = &lds[0][0][0]; char* lB0 = &lds[0][1][0];
    char* lA1 = &lds[1][0][0]; char* lB1 = &lds[1][1][0];

    i32x4 acc[2][4][2][2] = {};
    i32x4 a[4][2], b0[2][2], b1[2][2];

    // prologue: A0(0) B0(0) A1(0) B1(0) A0(1) B0(1)  -> 12 wave-loads
    stage_half(gA, 0, 0,   lA0, tid);
    stage_half(gB, 0, 0,   lB0, tid);
    stage_half(gA, 1, 0,   lA0, tid);
    stage_half(gB, 1, 0,   lB0, tid);
    stage_half(gA, 0, 128, lA1, tid);
    stage_half(gB, 0, 128, lB1, tid);
    asm volatile("s_waitcnt vmcnt(4)");   // kt=0 fully landed
    BAR();

    for (int it = 0; it < 16; ++it) {
        const int kt  = 2 * it;
        const int kb1 = ((kt + 1) & 31) * 128;
        const int kb2 = ((kt + 2) & 31) * 128;
        const int kb3 = ((kt + 3) & 31) * 128;

        // phase 1: read A0,B0 (buf0); stage A1(kt+1)->buf1
        read_A<0>(lA0, wr, lane, a);
        read_B<0>(lB0, wc, lane, b0);
        stage_half(gA, 1, kb1, lA1, tid);
        BAR();
        mfma_quad<0, 0>(acc, a, b0);
        BAR();

        // phase 2: read B1 (buf0); stage B1(kt+1)->buf1
        read_B<1>(lB0, wc, lane, b1);
        stage_half(gB, 1, kb1, lB1, tid);
        BAR();
        mfma_quad<0, 1>(acc, a, b1);
        BAR();

        // phase 3: read A1 (buf0); stage A0(kt+2)->buf0 (A0 region free since ph1)
        read_A<1>(lA0, wr, lane, a);
        stage_half(gA, 0, kb2, lA0, tid);
        BAR();
        mfma_quad<1, 0>(acc, a, b0);
        BAR();

        // phase 4: stage B0(kt+2)->buf0; fence for kt+1
        stage_half(gB, 0, kb2, lB0, tid);
        BAR();
        mfma_quad<1, 1>(acc, a, b1);
        asm volatile("s_waitcnt vmcnt(4)");   // kt+1 fully landed
        BAR();

        // phase 5: read A0,B0 (buf1); stage A1(kt+2)->buf0
        read_A<0>(lA1, wr, lane, a);
        read_B<0>(lB1, wc, lane, b0);
        stage_half(gA, 1, kb2, lA0, tid);
        BAR();
        mfma_quad<0, 0>(acc, a, b0);
        BAR();

        // phase 6: read B1 (buf1); stage B1(kt+2)->buf0
        read_B<1>(lB1, wc, lane, b1);
        stage_half(gB, 1, kb2, lB0, tid);
        BAR();
        mfma_quad<0, 1>(acc, a, b1);
        BAR();

        // phase 7: read A1 (buf1); stage A0(kt+3)->buf1
        read_A<1>(lA1, wr, lane, a);
        stage_half(gA, 0, kb3, lA1, tid);
        BAR();
        mfma_quad<1, 0>(acc, a, b0);
        BAR();

        // phase 8: stage B0(kt+3)->buf1; fence for kt+2
        stage_half(gB, 0, kb3, lB1, tid);
        BAR();
        mfma_quad<1, 1>(acc, a, b1);
        asm volatile("s_waitcnt vmcnt(4)");   // kt+2 fully landed
        BAR();
    }

    // epilogue: C/D layout col = lane&15, row = (lane>>4)*4 + reg; nt stores (no RFO fetch)
    #pragma unroll
    for (int mh = 0; mh < 2; ++mh)
        #pragma unroll
        for (int mf = 0; mf < 4; ++mf) {
            const int rm = tm * 256 + mh * 128 + wr * 64 + mf * 16 + ((lane >> 4) << 2);
            float qsv[4];
            #pragma unroll
            for (int r = 0; r < 4; ++r) qsv[r] = qs[rm + r];
            #pragma unroll
            for (int nh = 0; nh < 2; ++nh)
                #pragma unroll
                for (int nf = 0; nf < 2; ++nf) {
                    const int n = tn * 256 + nh * 128 + wc * 32 + nf * 16 + (lane & 15);
                    const float wn = wscale[n];
                    const float bn = bias[n];
                    #pragma unroll
                    for (int r = 0; r < 4; ++r) {
                        const float val = (float)acc[mh][mf][nh][nf][r] * (qsv[r] * wn) + bn;
                        __builtin_nontemporal_store(val, &y[(size_t)(rm + r) * ND + n]);
                    }
                }
        }
}

// ---------------- Fallback GEMM (no-workspace path): 128^2 m97 structure, reads w32 ----------------
__global__ __launch_bounds__(256, 2) void gemm_q8_fallback(
    const int8_t* __restrict__ q,
    const int* __restrict__ w32,
    const float* __restrict__ qs,
    const float* __restrict__ wscale,
    const float* __restrict__ bias,
    float* __restrict__ y)
{
    __shared__ int8_t lA[128 * 64];
    __shared__ int8_t lB[128 * 64];

    const int tid  = threadIdx.x;
    const int lane = tid & 63;
    const int wave = tid >> 6;
    const int wr   = wave >> 1;
    const int wc   = wave & 1;
    const int tn   = blockIdx.x;
    const int tm   = blockIdx.y;

    const int ci0  = wave * 2;
    const int off0 = ci0 * 1024 + lane * 16;
    const int r0   = off0 >> 6;
    const int c0   = off0 & 63;
    const int off1 = off0 + 1024;
    const int r1   = off1 >> 6;
    const int c1   = off1 & 63;

    const int8_t* gA0 = q + (size_t)(tm * 128 + r0) * KD + c0;
    const int8_t* gA1 = q + (size_t)(tm * 128 + r1) * KD + c1;

    const int brow  = tid >> 1;
    const int bhalf = tid & 1;
    const int* gW = w32 + (size_t)(tn * 128 + brow) * KD + bhalf * 32;

    i32x4 acc[4][4] = {};
    const int kc = (lane >> 4) * 16;
    const int rA = wr * 64 + (lane & 15);
    const int rB = wc * 64 + (lane & 15);

    for (int k0 = 0; k0 < KD; k0 += 64) {
        __builtin_amdgcn_global_load_lds((gp_t)(gA0 + k0), (lp_t)(lA + ci0 * 1024),        16, 0, 0);
        __builtin_amdgcn_global_load_lds((gp_t)(gA1 + k0), (lp_t)(lA + ci0 * 1024 + 1024), 16, 0, 0);
        int bw[8];
        #pragma unroll
        for (int u = 0; u < 8; ++u) {
            i32x4 a4 = *(const i32x4*)(gW + k0 + u * 4);
            bw[u] = (a4[0] & 255) | ((a4[1] & 255) << 8) | ((a4[2] & 255) << 16) | (a4[3] << 24);
        }
        *(i32x4*)(lB + brow * 64 + bhalf * 32)      = i32x4{bw[0], bw[1], bw[2], bw[3]};
        *(i32x4*)(lB + brow * 64 + bhalf * 32 + 16) = i32x4{bw[4], bw[5], bw[6], bw[7]};
        __syncthreads();

        i32x4 a[4], b[4];
        #pragma unroll
        for (int i = 0; i < 4; ++i) a[i] = *(const i32x4*)(lA + (rA + i * 16) * 64 + kc);
        #pragma unroll
        for (int j = 0; j < 4; ++j) b[j] = *(const i32x4*)(lB + (rB + j * 16) * 64 + kc);
        #pragma unroll
        for (int i = 0; i < 4; ++i)
            #pragma unroll
            for (int j = 0; j < 4; ++j)
                acc[i][j] = __builtin_amdgcn_mfma_i32_16x16x64_i8(a[i], b[j], acc[i][j], 0, 0, 0);
        __syncthreads();
    }

    const int cbase = tn * 128 + wc * 64 + (lane & 15);
    const int rbase = tm * 128 + wr * 64 + ((lane >> 4) << 2);
    #pragma unroll
    for (int j = 0; j < 4; ++j) {
        const int n  = cbase + j * 16;
        const float wn = wscale[n];
        const float bn = bias[n];
        #pragma unroll
        for (int i = 0; i < 4; ++i)
            #pragma unroll
            for (int r = 0; r < 4; ++r) {
                const int m = rbase + i * 16 + r;
                y[(size_t)m * ND + n] = (float)acc[i][j][r] * (qs[m] * wn) + bn;
            }
    }
}

extern "C" void kernel_launch(void* const* d_in, const int* in_sizes, int n_in,
                              void* d_out, int out_size, void* d_ws, size_t ws_size,
                              hipStream_t stream) {
    const float* x      = (const float*)d_in[0];
    const int*   w32    = (const int*)d_in[1];
    const float* wscale = (const float*)d_in[2];
    const float* bias   = (const float*)d_in[3];
    float*       y      = (float*)d_out;

    const size_t q_bytes  = (size_t)M_TOK * KD;
    const size_t s_bytes  = (size_t)M_TOK * sizeof(float);
    const size_t w8_bytes = (size_t)ND * KD;

    int8_t* qbuf   = (int8_t*)d_ws;
    float*  scales = (float*)((char*)d_ws + q_bytes);
    int8_t* w8     = (int8_t*)((char*)d_ws + q_bytes + s_bytes);

    if (ws_size >= q_bytes + s_bytes + w8_bytes) {
        prep_kernel<<<8192 + 4096, 256, 0, stream>>>(x, qbuf, scales, w32, w8);
        gemm_q8_8ph_kernel<<<512, 512, 0, stream>>>(qbuf, w8, scales, wscale, bias, y);
    } else {
        prep_kernel<<<8192, 256, 0, stream>>>(x, qbuf, scales, w32, w8);
        dim3 grid(ND / 128, M_TOK / 128);
        gemm_q8_fallback<<<grid, 256, 0, stream>>>(qbuf, w32, scales, wscale, bias, y);
    }
}